// Round 12
// baseline (32.087 us; speedup 1.0000x reference)
//
#include <hip/hip_runtime.h>

namespace {

constexpr int F   = 128;
constexpr int L   = 4096;
constexpr int TPB = 4;            // 64-row tiles per block
constexpr int NB  = 2048 / TPB;   // 512 blocks

using short8 = __attribute__((ext_vector_type(8))) short;
using f32x16 = __attribute__((ext_vector_type(16))) float;
using u32x4  = __attribute__((ext_vector_type(4))) unsigned int;

__device__ inline unsigned short f2bf(float x) {
    unsigned u = __builtin_bit_cast(unsigned, x);
    unsigned r = (u + 0x7fffu + ((u >> 16) & 1u)) >> 16;
    return (unsigned short)r;
}

__device__ inline unsigned pack2(float lo, float hi) {
    return (unsigned)f2bf(lo) | ((unsigned)f2bf(hi) << 16);
}

// Head-folded weights packed as 32x32x16 MFMA SECOND-operand fragments:
//   Wf[((cg*16 + S)*64 + l)*8 + j] = Wbar[k][n]
//   h = l>>5, n = cg*32 + (l&31), k = S*16 + h*8 + j
//   Wbar[k][n]: k<128 -> mean_h W_src[(h*128+n)*128+k]
//              k>=128 -> mean_h W_res[(h*128+n)*128+(k-128)]
__global__ void prep(const float* __restrict__ Wsrc,
                     const float* __restrict__ Wres,
                     const float* __restrict__ bias,
                     unsigned short* __restrict__ Wf,
                     float* __restrict__ bbar)
{
    int idx = blockIdx.x * 256 + threadIdx.x;
    if (idx < 2 * F * F) {
        int j  = idx & 7;
        int r2 = idx >> 3;
        int l  = r2 & 63;
        int c  = r2 >> 6;          // 0..63
        int cg = c >> 4;
        int S  = c & 15;
        int h  = l >> 5;
        int k  = S * 16 + h * 8 + j;
        int n  = (cg << 5) + (l & 31);
        int e  = k & (F - 1);
        const float* W = (k < F) ? Wsrc : Wres;
        float sum = 0.f;
#pragma unroll
        for (int hh = 0; hh < 8; ++hh) sum += W[(hh * F + n) * F + e];
        Wf[idx] = f2bf(sum * 0.125f);
    }
    if (idx < F) {
        float s = 0.f;
#pragma unroll
        for (int hh = 0; hh < 8; ++hh) s += bias[hh * F + idx];
        bbar[idx] = s * 0.125f;
    }
}

// Issue global loads for tile starting at row BASE: local rows 0..64 hold
// global rows BASE-1 .. BASE+63. Chunks 0..1023 by all threads (4 each),
// chunk 1024+t (last row) by threads 0..15. All wave-contiguous.
#define ISSUE_LOADS(BASE)                                                  \
    {                                                                      \
        _Pragma("unroll")                                                  \
        for (int i = 0; i < 4; ++i) {                                      \
            int c = i * 256 + t;                                           \
            long g = (BASE) - 1 + (c >> 4);                                \
            if (g < 0) g = 0;                                              \
            const float* src = loc + g * F + (c & 15) * 8;                 \
            sv[i * 2]     = *(const float4*)(src);                         \
            sv[i * 2 + 1] = *(const float4*)(src + 4);                     \
        }                                                                  \
        if (t < 16) {                                                      \
            const float* src = loc + ((BASE) + 63) * F + t * 8;            \
            hv0 = *(const float4*)(src);                                   \
            hv1 = *(const float4*)(src + 4);                               \
        }                                                                  \
    }

#define PACK_WRITE(BUF)                                                    \
    {                                                                      \
        _Pragma("unroll")                                                  \
        for (int i = 0; i < 4; ++i) {                                      \
            int c = i * 256 + t;                                           \
            int r = c >> 4, sl = c & 15;                                   \
            u32x4 pk;                                                      \
            pk[0] = pack2(sv[i * 2].x,     sv[i * 2].y);                   \
            pk[1] = pack2(sv[i * 2].z,     sv[i * 2].w);                   \
            pk[2] = pack2(sv[i * 2 + 1].x, sv[i * 2 + 1].y);               \
            pk[3] = pack2(sv[i * 2 + 1].z, sv[i * 2 + 1].w);               \
            *(u32x4*)((char*)As[BUF] + r * 256 + ((sl * 16) ^ ((r & 15) << 4))) = pk; \
        }                                                                  \
        if (t < 16) {                                                      \
            u32x4 pk;                                                      \
            pk[0] = pack2(hv0.x, hv0.y);                                   \
            pk[1] = pack2(hv0.z, hv0.w);                                   \
            pk[2] = pack2(hv1.x, hv1.y);                                   \
            pk[3] = pack2(hv1.z, hv1.w);                                   \
            *(u32x4*)((char*)As[BUF] + 64 * 256 + (t * 16)) = pk;          \
        }                                                                  \
    }

// Block = 4 consecutive 64-row tiles, double-buffered LDS, async-stage split:
// next tile's loads are in flight across current tile's MFMA + stores.
__global__ __launch_bounds__(256, 2)
void gat_pipe(const float* __restrict__ loc,
              const unsigned short* __restrict__ Wf,
              const float* __restrict__ bbar,
              float* __restrict__ out)
{
    __shared__ unsigned short As[2][65 * 128];   // 65 rows x 256B each, swizzled

    const int t    = threadIdx.x;
    const int lane = t & 63;
    const int cg   = t >> 6;       // col-group 0..3
    const int l31  = lane & 31;
    const int h    = lane >> 5;
    const long row0 = (long)blockIdx.x * (64 * TPB);

    // W slice: 16 x b128 lane-linear (64 VGPR, lives whole kernel)
    u32x4 wu[16];
#pragma unroll
    for (int s = 0; s < 16; ++s)
        wu[s] = *(const u32x4*)(Wf + (((cg * 16 + s) * 64 + lane) << 3));

    const float bb = bbar[cg * 32 + l31];

    float4 sv[8];
    float4 hv0, hv1;

    // prologue: stage tile 0
    ISSUE_LOADS(row0)
    asm volatile("" ::: "memory");
    PACK_WRITE(0)
    __syncthreads();

#pragma unroll
    for (int it = 0; it < TPB; ++it) {
        const long tbase = row0 + (long)it * 64;
        const int  buf   = it & 1;

        // async-stage: issue next tile's loads; they stay in flight across
        // MFMA + stores (the clobber pins issue order & blocks remat/sinking)
        if (it + 1 < TPB) ISSUE_LOADS(tbase + 64)
        asm volatile("" ::: "memory");

        f32x16 acc0, acc1;
#pragma unroll
        for (int i = 0; i < 16; ++i) { acc0[i] = 0.f; acc1[i] = 0.f; }

#pragma unroll
        for (int s = 0; s < 16; ++s) {
            const int d   = (s < 8) ? 0 : 1;     // s<8: prev row, s>=8: cur row
            const int off = (s & 7) * 32 + h * 16;
            const int r0  = l31 + d;
            const int r1  = 32 + l31 + d;
            short8 x0 = *(const short8*)((const char*)As[buf] + r0 * 256 + (off ^ ((r0 & 15) << 4)));
            short8 x1 = *(const short8*)((const char*)As[buf] + r1 * 256 + (off ^ ((r1 & 15) << 4)));
            short8 w  = __builtin_bit_cast(short8, wu[s]);
            acc0 = __builtin_amdgcn_mfma_f32_32x32x16_bf16(x0, w, acc0, 0, 0, 0);
            acc1 = __builtin_amdgcn_mfma_f32_32x32x16_bf16(x1, w, acc1, 0, 0, 0);
        }

        // stores: D col = lane&31 -> out-col; 2x128B contiguous per wave-instr
        const int col = cg * 32 + l31;
#pragma unroll
        for (int reg = 0; reg < 16; ++reg) {
            const int rl = (reg & 3) + 8 * (reg >> 2) + 4 * h;
            {
                long grow = tbase + rl;
                float v = acc0[reg] + bb;
                if ((grow & (L - 1)) == 0) v = loc[grow * F + col];  // out[b,0,:]=loc[b,0,:]
                out[grow * F + col] = v;
            }
            {
                long grow = tbase + 32 + rl;   // never p==0
                out[grow * F + col] = acc1[reg] + bb;
            }
        }

        if (it + 1 < TPB) {
            PACK_WRITE(buf ^ 1)      // waits vmcnt for the staged loads here
            __syncthreads();
        }
    }
}

} // namespace

extern "C" void kernel_launch(void* const* d_in, const int* in_sizes, int n_in,
                              void* d_out, int out_size, void* d_ws, size_t ws_size,
                              hipStream_t stream) {
    const float* loc  = (const float*)d_in[0];
    const float* Wsrc = (const float*)d_in[1];
    // d_in[2] W_dst, d_in[3] attn_l, d_in[4] attn_r cancel (alpha == 1)
    const float* Wres = (const float*)d_in[5];
    const float* bias = (const float*)d_in[6];

    unsigned short* Wf   = (unsigned short*)d_ws;          // 32768 bf16 = 64 KB
    float*          bbar = (float*)((char*)d_ws + 2 * F * F * 2);
    float*          outp = (float*)d_out;

    prep<<<128, 256, 0, stream>>>(Wsrc, Wres, bias, Wf, bbar);

    gat_pipe<<<NB, 256, 0, stream>>>(loc, Wf, bbar, outp);
}

// Round 13
// 31.328 us; speedup vs baseline: 1.0243x; 1.0243x over previous
//
#include <hip/hip_runtime.h>

namespace {

constexpr int F = 128;
constexpr int L = 4096;

using short8 = __attribute__((ext_vector_type(8))) short;
using f32x16 = __attribute__((ext_vector_type(16))) float;
using u32x4  = __attribute__((ext_vector_type(4))) unsigned int;

__device__ inline unsigned short f2bf(float x) {
    unsigned u = __builtin_bit_cast(unsigned, x);
    unsigned r = (u + 0x7fffu + ((u >> 16) & 1u)) >> 16;
    return (unsigned short)r;
}

__device__ inline unsigned pack2(float lo, float hi) {
    return (unsigned)f2bf(lo) | ((unsigned)f2bf(hi) << 16);
}

// Head-folded weights packed as 32x32x16 MFMA SECOND-operand fragments:
//   Wf[((cg*16 + S)*64 + l)*8 + j] = Wbar[kk][n]
//   with S=kk>>4, h=(kk>>3)&1, j=kk&7, l=h*32+(n&31), cg=n>>5
//   Wbar[kk][n]: kk<128 -> mean_h W_src[(h*128+n)*128+kk]
//               kk>=128 -> mean_h W_res[(h*128+n)*128+(kk-128)]
// Coalesced-read layout: thread idx -> (mat, n, k) with k = idx&127
__global__ void prep(const float* __restrict__ Wsrc,
                     const float* __restrict__ Wres,
                     const float* __restrict__ bias,
                     unsigned short* __restrict__ Wf,
                     float* __restrict__ bbar)
{
    int idx = blockIdx.x * 256 + threadIdx.x;
    if (idx < 2 * F * F) {
        int mat = idx >> 14;
        int rem = idx & 16383;
        int n   = rem >> 7;
        int k   = rem & 127;          // contiguous across lanes -> coalesced reads
        const float* W = mat ? Wres : Wsrc;
        float sum = 0.f;
#pragma unroll
        for (int hh = 0; hh < 8; ++hh) sum += W[(hh * F + n) * F + k];
        int kk = mat * 128 + k;
        int S  = kk >> 4;
        int h2 = (kk >> 3) & 1;
        int j  = kk & 7;
        int l  = h2 * 32 + (n & 31);
        int cg = n >> 5;
        Wf[(((cg * 16 + S) * 64 + l) << 3) + j] = f2bf(sum * 0.125f);
    }
    if (idx < F) {
        float s = 0.f;
#pragma unroll
        for (int hh = 0; hh < 8; ++hh) s += bias[hh * F + idx];
        bbar[idx] = s * 0.125f;
    }
}

// Block = 64 output rows x 128 cols, 4 waves (wave = 32-col group, 64 rows).
// All global accesses wave-contiguous; A via swizzled LDS; W in VGPRs;
// non-temporal stores keep dead write-data out of L2/L3 (protects loc).
__global__ __launch_bounds__(256, 3)
void gat_cg(const float* __restrict__ loc,
            const unsigned short* __restrict__ Wf,
            const float* __restrict__ bbar,
            float* __restrict__ out)
{
    __shared__ unsigned short As[65 * 128];   // 65 rows x 256B, XOR-swizzled

    const int t    = threadIdx.x;
    const int lane = t & 63;
    const int cg   = t >> 6;       // col-group 0..3
    const int l31  = lane & 31;
    const int h    = lane >> 5;
    const long rowbase = (long)blockIdx.x * 64;

    // ---- W slice: 16 x b128 lane-linear (64 VGPR, lives whole kernel)
    u32x4 wu[16];
#pragma unroll
    for (int s = 0; s < 16; ++s)
        wu[s] = *(const u32x4*)(Wf + (((cg * 16 + s) * 64 + lane) << 3));

    const float bb = bbar[cg * 32 + l31];

    // ---- stage A: global rows rowbase-1 .. rowbase+63 -> LDS rows 0..64
    // contiguous 32B/lane reads; bf16 + (row&15)<<4 XOR swizzle on write
#pragma unroll
    for (int i = 0; i < 5; ++i) {
        int c = i * 256 + t;
        if (i < 4 || c < 1040) {               // 65 rows * 16 chunks
            int r  = c >> 4;
            int sl = c & 15;
            long g = rowbase - 1 + r;
            if (g < 0) g = 0;                  // block-0 halo clamp (value unused)
            const float* src = loc + g * F + sl * 8;
            float4 v0 = *(const float4*)(src);
            float4 v1 = *(const float4*)(src + 4);
            u32x4 pk;
            pk[0] = pack2(v0.x, v0.y);
            pk[1] = pack2(v0.z, v0.w);
            pk[2] = pack2(v1.x, v1.y);
            pk[3] = pack2(v1.z, v1.w);
            *(u32x4*)((char*)As + r * 256 + ((sl * 16) ^ ((r & 15) << 4))) = pk;
        }
    }
    __syncthreads();

    // ---- compute: 2 row-tiles x 16 k-steps; s<8 uses prev rows (LDS r+0),
    // s>=8 uses cur rows (LDS r+1)
    f32x16 acc0, acc1;
#pragma unroll
    for (int i = 0; i < 16; ++i) { acc0[i] = 0.f; acc1[i] = 0.f; }

#pragma unroll
    for (int s = 0; s < 16; ++s) {
        const int d   = (s < 8) ? 0 : 1;
        const int off = (s & 7) * 32 + h * 16;
        const int r0  = l31 + d;
        const int r1  = 32 + l31 + d;
        short8 x0 = *(const short8*)((const char*)As + r0 * 256 + (off ^ ((r0 & 15) << 4)));
        short8 x1 = *(const short8*)((const char*)As + r1 * 256 + (off ^ ((r1 & 15) << 4)));
        short8 w  = __builtin_bit_cast(short8, wu[s]);
        acc0 = __builtin_amdgcn_mfma_f32_32x32x16_bf16(x0, w, acc0, 0, 0, 0);
        acc1 = __builtin_amdgcn_mfma_f32_32x32x16_bf16(x1, w, acc1, 0, 0, 0);
    }

    // ---- stores: D col = lane&31 -> out-col; 2x128B contiguous per instr.
    // Non-temporal: out is never re-read, keep it out of L2/L3.
    const int col = cg * 32 + l31;
    float* ob0 = out + (rowbase + 4 * h) * F + col;
    float* ob1 = ob0 + 32 * F;
#pragma unroll
    for (int reg = 0; reg < 16; ++reg) {
        const int rl = (reg & 3) + 8 * (reg >> 2);   // compile-time row offset
        __builtin_nontemporal_store(acc0[reg] + bb, ob0 + rl * F);
        __builtin_nontemporal_store(acc1[reg] + bb, ob1 + rl * F);
    }

    // ---- p==0 fixup: only row `rowbase` when rowbase%L==0; owned by h==0
    if (((rowbase & (L - 1)) == 0) && h == 0) {
        float v = loc[rowbase * F + col];
        __builtin_nontemporal_store(v, out + rowbase * F + col);  // out[b,0,:]=loc[b,0,:]
    }
}

} // namespace

extern "C" void kernel_launch(void* const* d_in, const int* in_sizes, int n_in,
                              void* d_out, int out_size, void* d_ws, size_t ws_size,
                              hipStream_t stream) {
    const float* loc  = (const float*)d_in[0];
    const float* Wsrc = (const float*)d_in[1];
    // d_in[2] W_dst, d_in[3] attn_l, d_in[4] attn_r cancel (alpha == 1)
    const float* Wres = (const float*)d_in[5];
    const float* bias = (const float*)d_in[6];

    unsigned short* Wf   = (unsigned short*)d_ws;          // 32768 bf16 = 64 KB
    float*          bbar = (float*)((char*)d_ws + 2 * F * F * 2);
    float*          outp = (float*)d_out;

    prep<<<128, 256, 0, stream>>>(Wsrc, Wres, bias, Wf, bbar);

    // 131072 rows / 64 rows per block = 2048 blocks
    gat_cg<<<2048, 256, 0, stream>>>(loc, Wf, bbar, outp);
}